// Round 4
// baseline (760.289 us; speedup 1.0000x reference)
//
#include <hip/hip_runtime.h>
#include <math.h>

#define T_TOK 4096
#define DM 1024
#define DF 4096
#define NE 8

#define BM 128
#define BN 128
#define BK 64   // bf16 elems per K-step; 128 B per LDS row; m97 structure

typedef __attribute__((ext_vector_type(8))) short bf16x8;
typedef __attribute__((ext_vector_type(4))) float f32x4;
typedef unsigned long long u64;

__device__ __forceinline__ unsigned short f2bf(float f) {
    union { float f; unsigned int u; } v; v.f = f;
    unsigned int r = v.u + 0x7FFFu + ((v.u >> 16) & 1u);
    return (unsigned short)(r >> 16);
}
__device__ __forceinline__ float bf2f(unsigned short u) {
    union { float f; unsigned int u; } v; v.u = ((unsigned int)u) << 16;
    return v.f;
}
__device__ __forceinline__ u64 pk4(float4 a) {
    return (u64)f2bf(a.x) | ((u64)f2bf(a.y) << 16) | ((u64)f2bf(a.z) << 32) | ((u64)f2bf(a.w) << 48);
}

__device__ __forceinline__ void glds16(const void* g, void* l) {
    __builtin_amdgcn_global_load_lds(
        (const __attribute__((address_space(1))) unsigned int*)g,
        (__attribute__((address_space(3))) unsigned int*)l, 16, 0, 0);
}

// ---------------- router (+ fused x f32->bf16 cast): 1 wave per token ----------------
__global__ __launch_bounds__(256) void k_router(
    const float* __restrict__ x, const float* __restrict__ noise,
    const float* __restrict__ Wg, const float* __restrict__ bg,
    const float* __restrict__ Wn, const float* __restrict__ bn,
    int* __restrict__ counts, int* __restrict__ slots, float* __restrict__ gates,
    unsigned short* __restrict__ xb)
{
    const int lane = threadIdx.x & 63;
    const int wave = threadIdx.x >> 6;
    const int t = blockIdx.x * 4 + wave;
    const float* xr = x + (size_t)t * DM;

    // coalesced: lane holds d = j*256 + lane*4 + jj (mapping is free under full-wave reduce)
    float4 xv[4];
    #pragma unroll
    for (int j = 0; j < 4; ++j) xv[j] = *(const float4*)(xr + j * 256 + lane * 4);
    #pragma unroll
    for (int j = 0; j < 4; ++j)
        *(u64*)(xb + (size_t)t * DM + j * 256 + lane * 4) = pk4(xv[j]);

    float accg[8], accn[8];
    #pragma unroll
    for (int i = 0; i < 8; ++i) { accg[i] = 0.f; accn[i] = 0.f; }

    #pragma unroll
    for (int j = 0; j < 4; ++j) {
        const float xs[4] = {xv[j].x, xv[j].y, xv[j].z, xv[j].w};
        #pragma unroll
        for (int jj = 0; jj < 4; ++jj) {
            int d = j * 256 + lane * 4 + jj;
            float xvv = xs[jj];
            float4 g0 = *(const float4*)(Wg + d * 8);
            float4 g1 = *(const float4*)(Wg + d * 8 + 4);
            float4 n0 = *(const float4*)(Wn + d * 8);
            float4 n1 = *(const float4*)(Wn + d * 8 + 4);
            accg[0] += xvv * g0.x; accg[1] += xvv * g0.y; accg[2] += xvv * g0.z; accg[3] += xvv * g0.w;
            accg[4] += xvv * g1.x; accg[5] += xvv * g1.y; accg[6] += xvv * g1.z; accg[7] += xvv * g1.w;
            accn[0] += xvv * n0.x; accn[1] += xvv * n0.y; accn[2] += xvv * n0.z; accn[3] += xvv * n0.w;
            accn[4] += xvv * n1.x; accn[5] += xvv * n1.y; accn[6] += xvv * n1.z; accn[7] += xvv * n1.w;
        }
    }
    #pragma unroll
    for (int s = 1; s < 64; s <<= 1) {
        #pragma unroll
        for (int e = 0; e < 8; ++e) {
            accg[e] += __shfl_xor(accg[e], s, 64);
            accn[e] += __shfl_xor(accn[e], s, 64);
        }
    }
    if (lane == 0) {
        float nv[8];
        #pragma unroll
        for (int e = 0; e < 8; ++e) {
            float lg = accg[e] + bg[e];
            float nl = accn[e] + bn[e];
            float sp = (nl > 20.f) ? nl : log1pf(expf(nl));
            nv[e] = lg + noise[(size_t)t * NE + e] * sp;
        }
        int i0 = 0;
        #pragma unroll
        for (int e = 1; e < 8; ++e) if (nv[e] > nv[i0]) i0 = e;
        int i1 = -1;
        #pragma unroll
        for (int e = 0; e < 8; ++e) {
            if (e == i0) continue;
            if (i1 < 0 || nv[e] > nv[i1]) i1 = e;
        }
        float ex = expf(nv[i1] - nv[i0]);     // <= 1
        float g0 = 1.f / (1.f + ex);
        float g1 = ex / (1.f + ex);
        int p0 = atomicAdd(counts + i0, 1);
        slots[i0 * T_TOK + p0] = t * 2;     gates[i0 * T_TOK + p0] = g0;
        int p1 = atomicAdd(counts + i1, 1);
        slots[i1 * T_TOK + p1] = t * 2 + 1; gates[i1 * T_TOK + p1] = g1;
    }
}

// ---------------- transpose+convert: in [E][R][C] f32 -> out [E][C][R] bf16 ----------------
__global__ __launch_bounds__(256) void k_tr(const float* __restrict__ in,
                                            unsigned short* __restrict__ out,
                                            int R, int C)
{
    __shared__ unsigned short t[64 * 68];
    const int e = blockIdx.z;
    const int C0 = blockIdx.x * 64, R0 = blockIdx.y * 64;
    const float* ip = in + ((size_t)e * R + R0) * C + C0;
    unsigned short* op = out + ((size_t)e * C + C0) * R + R0;
    const int tid = threadIdx.x;

    #pragma unroll
    for (int p = 0; p < 4; ++p) {
        int r = p * 16 + (tid >> 4), c4 = (tid & 15) * 4;
        float4 v = *(const float4*)(ip + (size_t)r * C + c4);
        t[(c4 + 0) * 68 + r] = f2bf(v.x);
        t[(c4 + 1) * 68 + r] = f2bf(v.y);
        t[(c4 + 2) * 68 + r] = f2bf(v.z);
        t[(c4 + 3) * 68 + r] = f2bf(v.w);
    }
    __syncthreads();
    #pragma unroll
    for (int p = 0; p < 4; ++p) {
        int c = p * 16 + (tid >> 4), r4 = (tid & 15) * 4;
        u64 v = *(const u64*)(t + c * 68 + r4);
        *(u64*)(op + (size_t)c * R + r4) = v;
    }
}

// ---------------- fc1: h[off[e]+gi] = relu(x_bf[tok] @ W1t^T + b1) ----------------
// W1t layout: [E][F][D] bf16. grid = (NE, DF/BN, T/BM). m97-style K-loop.
__global__ __launch_bounds__(256, 4) void k_fc1(
    const unsigned short* __restrict__ xb, const unsigned short* __restrict__ W1t,
    const float* __restrict__ b1, const int* __restrict__ counts,
    const int* __restrict__ slots, unsigned short* __restrict__ h)
{
    const int e = blockIdx.x;          // expert -> XCD affinity
    const int cnt = counts[e];
    const int mt = blockIdx.z;
    if (mt * BM >= cnt) return;
    const int nb = blockIdx.y * BN;

    int offE = 0;
    for (int i = 0; i < e; ++i) offE += counts[i];

    __shared__ unsigned short As[BM * BK];
    __shared__ unsigned short Bs[BN * BK];
    __shared__ int slot_s[BM];

    const int tid = threadIdx.x;
    if (tid < BM) {
        int gi = mt * BM + tid;
        slot_s[tid] = (gi < cnt) ? slots[e * T_TOK + gi] : -1;
    }
    __syncthreads();

    // staging: thread -> row = cc*32 + (tid>>3), phys chunk = tid&7,
    // global chunk g = (tid&7) ^ ((tid>>3)&7)  (row&7 == (tid>>3)&7 for all cc)
    const int lane = tid & 63, wv = tid >> 6;
    const int srow = tid >> 3;
    const int g = (tid & 7) ^ (srow & 7);

    const unsigned short* agp[4];
    const unsigned short* bgp[4];
    const unsigned short* wbase = W1t + (size_t)e * DF * DM;
    #pragma unroll
    for (int cc = 0; cc < 4; ++cc) {
        int row = cc * 32 + srow;
        int s = slot_s[row];
        int tok = (s >= 0) ? (s >> 1) : 0;
        agp[cc] = xb + (size_t)tok * DM + g * 8;
        bgp[cc] = wbase + (size_t)(nb + row) * DM + g * 8;
    }
    unsigned short* al = As + wv * 512;   // + cc*2048; lane*16B implicit
    unsigned short* bl = Bs + wv * 512;

    const int wm = (wv & 1) * 64, wn = (wv >> 1) * 64;
    const int ml = lane & 15, kg = lane >> 4;

    f32x4 acc[4][4];
    #pragma unroll
    for (int ni = 0; ni < 4; ++ni)
        #pragma unroll
        for (int mi = 0; mi < 4; ++mi) acc[ni][mi] = (f32x4){0.f, 0.f, 0.f, 0.f};

    for (int k0 = 0; k0 < DM; k0 += BK) {
        #pragma unroll
        for (int cc = 0; cc < 4; ++cc) glds16(agp[cc] + k0, al + cc * 2048);
        #pragma unroll
        for (int cc = 0; cc < 4; ++cc) glds16(bgp[cc] + k0, bl + cc * 2048);
        __syncthreads();
        #pragma unroll
        for (int ks = 0; ks < 2; ++ks) {
            const int rch = (((ks * 4 + kg) ^ (ml & 7)) << 3);
            bf16x8 af[4], bfr[4];
            #pragma unroll
            for (int mi = 0; mi < 4; ++mi)
                af[mi] = *(const bf16x8*)(As + (wm + mi * 16 + ml) * BK + rch);
            #pragma unroll
            for (int ni = 0; ni < 4; ++ni)
                bfr[ni] = *(const bf16x8*)(Bs + (wn + ni * 16 + ml) * BK + rch);
            #pragma unroll
            for (int ni = 0; ni < 4; ++ni)
                #pragma unroll
                for (int mi = 0; mi < 4; ++mi)
                    acc[ni][mi] = __builtin_amdgcn_mfma_f32_16x16x32_bf16(bfr[ni], af[mi], acc[ni][mi], 0, 0, 0);
        }
        __syncthreads();
    }

    // D layout (swapped operands): col=ml -> token row of tile; row=kg*4+j -> n
    #pragma unroll
    for (int mi = 0; mi < 4; ++mi) {
        int row = wm + mi * 16 + ml;
        int s = slot_s[row];
        if (s < 0) continue;
        unsigned short* hrow = h + (size_t)(offE + mt * BM + row) * DF + nb;
        #pragma unroll
        for (int ni = 0; ni < 4; ++ni) {
            int n0 = wn + ni * 16 + kg * 4;
            float4 bb = *(const float4*)(b1 + (size_t)e * DF + nb + n0);
            float v0 = fmaxf(acc[ni][mi][0] + bb.x, 0.f);
            float v1 = fmaxf(acc[ni][mi][1] + bb.y, 0.f);
            float v2 = fmaxf(acc[ni][mi][2] + bb.z, 0.f);
            float v3 = fmaxf(acc[ni][mi][3] + bb.w, 0.f);
            u64 p = (u64)f2bf(v0) | ((u64)f2bf(v1) << 16) | ((u64)f2bf(v2) << 32) | ((u64)f2bf(v3) << 48);
            *(u64*)(hrow + n0) = p;
        }
    }
}

// ---------------- fc2: eo[kz][slot] = gate*(h_compact @ W2t^T + b2*(kz==0)) ----------------
// W2t layout: [E][D][F] bf16. grid = (NE, DM/BN, (T/BM)*2)
__global__ __launch_bounds__(256, 4) void k_fc2(
    const unsigned short* __restrict__ h, const unsigned short* __restrict__ W2t,
    const float* __restrict__ b2, const int* __restrict__ counts,
    const int* __restrict__ slots, const float* __restrict__ gates,
    unsigned short* __restrict__ eo)
{
    const int e = blockIdx.x;
    const int cnt = counts[e];
    const int mt = blockIdx.z >> 1;
    const int kz = blockIdx.z & 1;
    if (mt * BM >= cnt) return;
    const int nb = blockIdx.y * BN;

    int offE = 0;
    for (int i = 0; i < e; ++i) offE += counts[i];

    __shared__ unsigned short As[BM * BK];
    __shared__ unsigned short Bs[BN * BK];
    __shared__ int slot_s[BM];
    __shared__ float gate_s[BM];

    const int tid = threadIdx.x;
    if (tid < BM) {
        int gi = mt * BM + tid;
        if (gi < cnt) {
            slot_s[tid] = slots[e * T_TOK + gi];
            gate_s[tid] = gates[e * T_TOK + gi];
        } else { slot_s[tid] = -1; gate_s[tid] = 0.f; }
    }
    __syncthreads();

    const int lane = tid & 63, wv = tid >> 6;
    const int srow = tid >> 3;
    const int g = (tid & 7) ^ (srow & 7);
    const int kbeg = kz * (DF / 2);

    const unsigned short* agp[4];
    const unsigned short* bgp[4];
    const unsigned short* wbase = W2t + (size_t)e * DM * DF;
    #pragma unroll
    for (int cc = 0; cc < 4; ++cc) {
        int row = cc * 32 + srow;
        int gi = mt * BM + row;
        int gpos = offE + ((gi < cnt) ? gi : 0);   // positional, contiguous
        agp[cc] = h + (size_t)gpos * DF + kbeg + g * 8;
        bgp[cc] = wbase + (size_t)(nb + row) * DF + kbeg + g * 8;
    }
    unsigned short* al = As + wv * 512;
    unsigned short* bl = Bs + wv * 512;

    const int wm = (wv & 1) * 64, wn = (wv >> 1) * 64;
    const int ml = lane & 15, kg = lane >> 4;

    f32x4 acc[4][4];
    #pragma unroll
    for (int ni = 0; ni < 4; ++ni)
        #pragma unroll
        for (int mi = 0; mi < 4; ++mi) acc[ni][mi] = (f32x4){0.f, 0.f, 0.f, 0.f};

    for (int k0 = 0; k0 < DF / 2; k0 += BK) {
        #pragma unroll
        for (int cc = 0; cc < 4; ++cc) glds16(agp[cc] + k0, al + cc * 2048);
        #pragma unroll
        for (int cc = 0; cc < 4; ++cc) glds16(bgp[cc] + k0, bl + cc * 2048);
        __syncthreads();
        #pragma unroll
        for (int ks = 0; ks < 2; ++ks) {
            const int rch = (((ks * 4 + kg) ^ (ml & 7)) << 3);
            bf16x8 af[4], bfr[4];
            #pragma unroll
            for (int mi = 0; mi < 4; ++mi)
                af[mi] = *(const bf16x8*)(As + (wm + mi * 16 + ml) * BK + rch);
            #pragma unroll
            for (int ni = 0; ni < 4; ++ni)
                bfr[ni] = *(const bf16x8*)(Bs + (wn + ni * 16 + ml) * BK + rch);
            #pragma unroll
            for (int ni = 0; ni < 4; ++ni)
                #pragma unroll
                for (int mi = 0; mi < 4; ++mi)
                    acc[ni][mi] = __builtin_amdgcn_mfma_f32_16x16x32_bf16(bfr[ni], af[mi], acc[ni][mi], 0, 0, 0);
        }
        __syncthreads();
    }

    unsigned short* eob = eo + (size_t)kz * 2 * T_TOK * DM;
    #pragma unroll
    for (int mi = 0; mi < 4; ++mi) {
        int row = wm + mi * 16 + ml;
        int s = slot_s[row];
        if (s < 0) continue;
        float gg = gate_s[row];
        #pragma unroll
        for (int ni = 0; ni < 4; ++ni) {
            int n0 = wn + ni * 16 + kg * 4;
            float4 bb;
            if (kz == 0) bb = *(const float4*)(b2 + (size_t)e * DM + nb + n0);
            else         bb = make_float4(0.f, 0.f, 0.f, 0.f);
            float v0 = gg * (acc[ni][mi][0] + bb.x);
            float v1 = gg * (acc[ni][mi][1] + bb.y);
            float v2 = gg * (acc[ni][mi][2] + bb.z);
            float v3 = gg * (acc[ni][mi][3] + bb.w);
            u64 p = (u64)f2bf(v0) | ((u64)f2bf(v1) << 16) | ((u64)f2bf(v2) << 32) | ((u64)f2bf(v3) << 48);
            *(u64*)(eob + (size_t)s * DM + nb + n0) = p;
        }
    }
}

// ---------------- combine: out[t] = sum over {kz} x {2t,2t+1} of eo ----------------
__global__ __launch_bounds__(256) void k_comb(const unsigned short* __restrict__ eo,
                                              float* __restrict__ out)
{
    int i = blockIdx.x * 256 + threadIdx.x;   // float4 index over T*DM/4
    int t = i >> 8;                           // DM/4 = 256
    int d4 = (i & 255) * 4;
    const unsigned short* p0 = eo + (size_t)(2 * t) * DM + d4;
    const unsigned short* p1 = p0 + DM;
    const unsigned short* q0 = p0 + (size_t)2 * T_TOK * DM;
    const unsigned short* q1 = q0 + DM;
    ushort4 a0 = *(const ushort4*)p0;
    ushort4 a1 = *(const ushort4*)p1;
    ushort4 b0 = *(const ushort4*)q0;
    ushort4 b1 = *(const ushort4*)q1;
    float4 r;
    r.x = bf2f(a0.x) + bf2f(a1.x) + bf2f(b0.x) + bf2f(b1.x);
    r.y = bf2f(a0.y) + bf2f(a1.y) + bf2f(b0.y) + bf2f(b1.y);
    r.z = bf2f(a0.z) + bf2f(a1.z) + bf2f(b0.z) + bf2f(b1.z);
    r.w = bf2f(a0.w) + bf2f(a1.w) + bf2f(b0.w) + bf2f(b1.w);
    ((float4*)out)[i] = r;
}

extern "C" void kernel_launch(void* const* d_in, const int* in_sizes, int n_in,
                              void* d_out, int out_size, void* d_ws, size_t ws_size,
                              hipStream_t stream) {
    const float* x     = (const float*)d_in[0];
    const float* noise = (const float*)d_in[1];
    const float* Wg    = (const float*)d_in[2];
    const float* bg    = (const float*)d_in[3];
    const float* Wn    = (const float*)d_in[4];
    const float* bn    = (const float*)d_in[5];
    const float* W1    = (const float*)d_in[6];
    const float* b1    = (const float*)d_in[7];
    const float* W2    = (const float*)d_in[8];
    const float* b2    = (const float*)d_in[9];
    float* out = (float*)d_out;

    char* ws = (char*)d_ws;
    int*   counts = (int*)ws;                                    // 4 KiB
    int*   slots  = (int*)(ws + 4096);                           // [E][T] 128 KiB
    float* gates  = (float*)(ws + 4096 + NE * T_TOK * 4);        // [E][T] 128 KiB
    unsigned short* xb = (unsigned short*)(ws + 4096 + 2 * NE * T_TOK * 4); // [T][D] bf16, 8 MB
    unsigned short* hh = xb + (size_t)T_TOK * DM;                // [8192][F] bf16 (compact), 67 MB
    unsigned short* Wt = hh + (size_t)2 * T_TOK * DF;            // bf16, 67 MB (W1t then W2t)
    unsigned short* eo = Wt + (size_t)NE * DM * DF;              // [2][2T][D] bf16, 34 MB

    hipMemsetAsync(counts, 0, 4096, stream);

    k_router<<<T_TOK / 4, 256, 0, stream>>>(x, noise, Wg, bg, Wn, bn, counts, slots, gates, xb);

    // W1 [E][D][F] -> Wt [E][F][D]
    k_tr<<<dim3(DF / 64, DM / 64, NE), 256, 0, stream>>>(W1, Wt, DM, DF);
    k_fc1<<<dim3(NE, DF / BN, T_TOK / BM), 256, 0, stream>>>(xb, Wt, b1, counts, slots, hh);

    // W2 [E][F][D] -> Wt [E][D][F]
    k_tr<<<dim3(DM / 64, DF / 64, NE), 256, 0, stream>>>(W2, Wt, DF, DM);
    k_fc2<<<dim3(NE, DM / BN, (T_TOK / BM) * 2), 256, 0, stream>>>(hh, Wt, b2, counts, slots, gates, eo);

    k_comb<<<T_TOK * DM / 1024, 256, 0, stream>>>(eo, out);
}